// Round 9
// baseline (547.035 us; speedup 1.0000x reference)
//
#include <hip/hip_runtime.h>
#include <math.h>
#include <float.h>

#define VOCAB    32000
#define NT       256
#define NWAVES   (NT / 64)
#define CAP      1024    // candidate buffer; E[count]=228 at THETA0
#define KMAX     64      // >= top_k (50)
#define KREF     24.0f
#define THETA0   14.0f
#define LOG2E    1.4426950408889634f
#define THT      ((THETA0 - KREF) * LOG2E)
#define FBDELTA  (12.0f * LOG2E)
#define NCHUNK   (VOCAB / 4)   // 8000 float4 per row
#define DEPTH    4             // per-wave DMA ring slots (1KB each)

typedef float vf4 __attribute__((ext_vector_type(4)));
typedef const __attribute__((address_space(1))) void g1v;
typedef __attribute__((address_space(3))) void l3v;

// R9 probe: async global->LDS DMA streaming. R0-R8 evidence: reads pinned at
// ~1.6-1.7 TB/s across VALU cost, address phase, nt policy, MLP depth, and
// stream topology, while fills WRITE 6.6 TB/s. Plain (50% L3-hit) and nt
// (HBM-direct) land at the SAME rate -> cap is the CU-side read-return path
// (L1 MSHR/VGPR writeback), not the service legs. global_load_lds returns data
// fabric->LDS directly (no VGPR writeback, different queue) -- the one distinct
// mechanism untested. Per-wave private 4x1KB ring, counted vmcnt(3), consume
// via ds_read_b128. Per-thread element set/order bitwise identical to R5
// (chunk c = wid+4i, lane-linear), so outputs are unchanged.

#define PROCESS(v, jj)                                                              \
    {                                                                               \
        float t0 = fmaf((v).x, a, b);                                               \
        float t1 = fmaf((v).y, a, b);                                               \
        float t2 = fmaf((v).z, a, b);                                               \
        float t3 = fmaf((v).w, a, b);                                               \
        sA += exp2f(t0);                                                            \
        sB += exp2f(t1);                                                            \
        sA += exp2f(t2);                                                            \
        sB += exp2f(t3);                                                            \
        tmax = fmaxf(tmax, fmaxf(fmaxf(t0, t1), fmaxf(t2, t3)));                    \
        int bi = (jj) * 4;                                                          \
        if (t0 > THT) { int p = atomicAdd(&s_cnt, 1); if (p < CAP) { s_val[p] = (v).x / T; s_idx[p] = bi;     } } \
        if (t1 > THT) { int p = atomicAdd(&s_cnt, 1); if (p < CAP) { s_val[p] = (v).y / T; s_idx[p] = bi + 1; } } \
        if (t2 > THT) { int p = atomicAdd(&s_cnt, 1); if (p < CAP) { s_val[p] = (v).z / T; s_idx[p] = bi + 2; } } \
        if (t3 > THT) { int p = atomicAdd(&s_cnt, 1); if (p < CAP) { s_val[p] = (v).w / T; s_idx[p] = bi + 3; } } \
    }

// issue DMA of chunk (c = wid+4k): 64 lanes x 16B -> slot (k&3) of this wave's ring
#define ISSUE(k)                                                                    \
    {                                                                               \
        const float* gp = logits + base + 4u * ((size_t)(wid + 4 * (k)) * 64 + lane); \
        __builtin_amdgcn_global_load_lds((g1v*)gp,                                  \
            (l3v*)&stage[(wid << 10) + (((k) & 3) << 8)], 16, 0, 0);                \
    }

// consume chunk i from slot (i&3); element/order identical to R5's j = tid + 256*i
#define CONSUME(i)                                                                  \
    {                                                                               \
        vf4 v = *(const vf4*)&stage[(wid << 10) + (((i) & 3) << 8) + (lane << 2)];  \
        PROCESS(v, (wid + 4 * (i)) * 64 + lane);                                    \
    }

__global__ __launch_bounds__(NT, 6) void dream_row_kernel(
    const float* __restrict__ logits,
    const float* __restrict__ gumbel,
    const float* __restrict__ tempP,
    const float* __restrict__ toppP,
    const int*   __restrict__ topkP,
    float* __restrict__ out_conf,
    float* __restrict__ out_x0,
    float* __restrict__ out_iconf)
{
    const int row = blockIdx.x;
    const int tid = threadIdx.x;
    const int lane = tid & 63;
    const int wid  = tid >> 6;
    const size_t base = (size_t)row * VOCAB;
    const float T = tempP[0];
    const float a = (1.0f / T) * LOG2E;
    const float b = -(KREF * LOG2E);

    __shared__ float stage[NT * DEPTH * 4];   // 4 waves x 4 slots x 1KB = 16KB
    __shared__ float s_val[CAP];              // exact x = v/T for candidates
    __shared__ int   s_idx[CAP];
    __shared__ int   s_cnt;
    __shared__ float wsum[NWAVES], wmax[NWAVES];
    __shared__ float sh_S, sh_m;
    __shared__ float so_val[KMAX];
    __shared__ int   so_idx[KMAX];
    __shared__ int   sh_nk;
    __shared__ float sh_skept;

    if (tid == 0) s_cnt = 0;
    __syncthreads();

    // ---- streaming pass: per-wave 4-deep DMA ring, counted vmcnt ----
    float sA = 0.0f, sB = 0.0f;
    float tmax = -FLT_MAX;
    const int nq = (wid == 0) ? 32 : 31;   // chunks per wave (8000 = 125 chunks; c=124 -> wave 0)

    asm volatile("s_waitcnt vmcnt(0)" ::: "memory");   // zero baseline for counted waits
    ISSUE(0); ISSUE(1); ISSUE(2); ISSUE(3);

    for (int i = 0; i + 4 < nq; ++i) {
        asm volatile("s_waitcnt vmcnt(3)" ::: "memory");   // chunk i arrived
        __builtin_amdgcn_sched_barrier(0);
        CONSUME(i);
        asm volatile("s_waitcnt lgkmcnt(0)" ::: "memory"); // ds_read retired before slot reuse
        __builtin_amdgcn_sched_barrier(0);
        ISSUE(i + 4);
    }
    asm volatile("s_waitcnt vmcnt(3)" ::: "memory"); __builtin_amdgcn_sched_barrier(0); CONSUME(nq - 4);
    asm volatile("s_waitcnt vmcnt(2)" ::: "memory"); __builtin_amdgcn_sched_barrier(0); CONSUME(nq - 3);
    asm volatile("s_waitcnt vmcnt(1)" ::: "memory"); __builtin_amdgcn_sched_barrier(0); CONSUME(nq - 2);
    asm volatile("s_waitcnt vmcnt(0)" ::: "memory"); __builtin_amdgcn_sched_barrier(0); CONSUME(nq - 1);

    // ---- wave-shuffle reduce, then tiny cross-wave combine ----
    float s = sA + sB;
    float mx = tmax;
    #pragma unroll
    for (int o = 32; o > 0; o >>= 1) {
        s  += __shfl_down(s, o, 64);
        mx  = fmaxf(mx, __shfl_down(mx, o, 64));
    }
    if (lane == 0) { wsum[wid] = s; wmax[wid] = mx; }
    __syncthreads();
    if (tid == 0) {
        float St = 0.0f, Mt = -FLT_MAX;
        #pragma unroll
        for (int w = 0; w < NWAVES; ++w) { St += wsum[w]; Mt = fmaxf(Mt, wmax[w]); }
        sh_S = St; sh_m = Mt;
    }
    __syncthreads();
    const float S_K = sh_S;
    const float m_t = sh_m;
    int C = min(s_cnt, CAP);

    // ---- rare fallback: fixed theta missed — recollect with adaptive theta ----
    if (C < KMAX) {
        if (tid == 0) s_cnt = 0;
        __syncthreads();
        const float th2t = m_t - FBDELTA;
        const vf4* l4 = (const vf4*)(logits + base);
        for (int j = tid; j < NCHUNK; j += NT) {
            vf4 v = l4[j];
            float t0 = fmaf(v.x, a, b);
            float t1 = fmaf(v.y, a, b);
            float t2 = fmaf(v.z, a, b);
            float t3 = fmaf(v.w, a, b);
            int bi = j * 4;
            if (t0 > th2t) { int p = atomicAdd(&s_cnt, 1); if (p < CAP) { s_val[p] = v.x / T; s_idx[p] = bi;     } }
            if (t1 > th2t) { int p = atomicAdd(&s_cnt, 1); if (p < CAP) { s_val[p] = v.y / T; s_idx[p] = bi + 1; } }
            if (t2 > th2t) { int p = atomicAdd(&s_cnt, 1); if (p < CAP) { s_val[p] = v.z / T; s_idx[p] = bi + 2; } }
            if (t3 > th2t) { int p = atomicAdd(&s_cnt, 1); if (p < CAP) { s_val[p] = v.w / T; s_idx[p] = bi + 3; } }
        }
        __syncthreads();
        C = min(s_cnt, CAP);
    }

    // ---- rank candidates on exact x (stable: value desc, index asc); keep top-KMAX ----
    for (int c = tid; c < C; c += NT) {
        float vc = s_val[c]; int ic = s_idx[c];
        int r = 0;
        #pragma unroll 4
        for (int j = 0; j < C; ++j) {
            float vj = s_val[j];
            if (vj > vc || (vj == vc && s_idx[j] < ic)) r++;
        }
        if (r < KMAX) { so_val[r] = vc; so_idx[r] = ic; }
    }
    __syncthreads();

    // ---- top-p prefix walk + top-k cap; replicate reference addition order ----
    if (tid == 0) {
        int k = topkP[0]; if (k > KMAX) k = KMAX; if (k < 1) k = 1;
        const float topp = toppP[0];
        const int lim = min(C, k);
        float cum = 0.0f;
        float skept = 0.0f;
        int nk = 0;
        for (int j = 0; j < lim; ++j) {
            if (cum > topp) break;
            float e = exp2f(fmaf(so_val[j], LOG2E, b));
            cum += e / S_K;
            skept += e;
            nk++;
        }
        sh_nk = nk;
        sh_skept = skept;
    }
    __syncthreads();
    const int nk = sh_nk;
    const float skept = sh_skept;

    // ---- Gumbel argmax over kept tokens (wave 0 only; first-index tie-break) ----
    if (wid == 0) {
        float bv = -FLT_MAX; int bi = 0x7FFFFFFF; float bx = 0.0f;
        if (lane < nk) {
            int gi = so_idx[lane];
            bx = so_val[lane];
            bv = bx + gumbel[base + gi];
            bi = gi;
        }
        #pragma unroll
        for (int o = 32; o > 0; o >>= 1) {
            float ov = __shfl_down(bv, o, 64);
            int   oi = __shfl_down(bi, o, 64);
            float ox = __shfl_down(bx, o, 64);
            if (ov > bv || (ov == bv && oi < bi)) { bv = ov; bi = oi; bx = ox; }
        }
        if (lane == 0) {
            float eb = exp2f(fmaf(bx, LOG2E, b));
            float confv = eb / skept;
            out_conf[row]  = confv;
            out_x0[row]    = (float)bi;
            out_iconf[row] = confv;
        }
    }
}

// Global accept step: any(conf > thr) ? per-row high : one-hot at argmax(conf)
__global__ __launch_bounds__(NT) void accept_kernel(
    const float* __restrict__ conf,
    const float* __restrict__ thrP,
    float* __restrict__ acc_out,
    int N)
{
    __shared__ float rv[NT];
    __shared__ int   ri[NT];
    __shared__ int   ra[NT];
    const int tid = threadIdx.x;
    const float thr = thrP[0];

    float bv = -FLT_MAX; int bi = 0x7FFFFFFF; int any = 0;
    for (int i = tid; i < N; i += NT) {
        float v = conf[i];
        if (v > thr) any = 1;
        if (v > bv) { bv = v; bi = i; }
    }
    rv[tid] = bv; ri[tid] = bi; ra[tid] = any;
    __syncthreads();
    #pragma unroll
    for (int s = NT / 2; s > 0; s >>= 1) {
        if (tid < s) {
            float ov = rv[tid + s]; int oi = ri[tid + s];
            if (ov > rv[tid] || (ov == rv[tid] && oi < ri[tid])) {
                rv[tid] = ov; ri[tid] = oi;
            }
            ra[tid] |= ra[tid + s];
        }
        __syncthreads();
    }
    const int anyHigh = ra[0];
    const int amax = ri[0];
    for (int i = tid; i < N; i += NT) {
        float a;
        if (anyHigh) a = (conf[i] > thr) ? 1.0f : 0.0f;
        else         a = (i == amax) ? 1.0f : 0.0f;
        acc_out[i] = a;
    }
}

extern "C" void kernel_launch(void* const* d_in, const int* in_sizes, int n_in,
                              void* d_out, int out_size, void* d_ws, size_t ws_size,
                              hipStream_t stream)
{
    const float* logits = (const float*)d_in[0];
    const float* gumbel = (const float*)d_in[1];
    const float* tempP  = (const float*)d_in[2];
    const float* toppP  = (const float*)d_in[3];
    const int*   topkP  = (const int*)d_in[4];
    const float* thrP   = (const float*)d_in[5];
    float* out = (float*)d_out;
    const int N = in_sizes[0] / VOCAB;

    dream_row_kernel<<<N, NT, 0, stream>>>(
        logits, gumbel, tempP, toppP, topkP,
        out /*confidence*/, out + N /*x0*/, out + 2 * N /*initial_confidence*/);

    accept_kernel<<<1, NT, 0, stream>>>(
        out, thrP, out + 3 * N /*accepted*/, N);
}